// Round 1
// baseline (397.702 us; speedup 1.0000x reference)
//
#include <hip/hip_runtime.h>
#include <hip/hip_bf16.h>

typedef __attribute__((ext_vector_type(8))) short bf16x8;
typedef __attribute__((ext_vector_type(4))) float f32x4;

#define MFMA16(a, b, c) __builtin_amdgcn_mfma_f32_16x16x32_bf16((a), (b), (c), 0, 0, 0)

__device__ __forceinline__ unsigned short f2bf(float f) {
  unsigned int x = __float_as_uint(f);
  x += 0x7fffu + ((x >> 16) & 1u);
  return (unsigned short)(x >> 16);
}

// C[m][n] = sum_k A[m][k] * B[n][k]   (A: fp32 or bf16-bits, B: fp32, C: fp32 or bf16-bits)
template <bool A_BF16, bool C_BF16>
__global__ __launch_bounds__(256) void gemm_abt(const void* __restrict__ Aptr,
                                                const float* __restrict__ Bptr,
                                                void* __restrict__ Cptr, int M, int N, int K) {
  __shared__ unsigned short Alds[128][40];
  __shared__ unsigned short Blds[128][40];
  const int tid = threadIdx.x;
  const int wid = tid >> 6, lane = tid & 63;
  const int lg = lane >> 4, lr = lane & 15;
  const int wr = wid >> 1, wc = wid & 1;
  const int bm = blockIdx.y, bn = blockIdx.x;

  f32x4 acc[4][4];
#pragma unroll
  for (int i = 0; i < 4; ++i)
#pragma unroll
    for (int j = 0; j < 4; ++j) acc[i][j] = {0.f, 0.f, 0.f, 0.f};

  const int srow = tid >> 1, sseg = tid & 1;
  const int nk = K >> 5;
  for (int kt = 0; kt < nk; ++kt) {
    __syncthreads();
    {
      // ---- stage A tile (128 x 32) as bf16 ----
      unsigned short* dstA = &Alds[srow][sseg * 16];
      if constexpr (A_BF16) {
        const unsigned short* src = (const unsigned short*)Aptr +
                                    (size_t)(bm * 128 + srow) * K + kt * 32 + sseg * 16;
        ((uint4*)dstA)[0] = ((const uint4*)src)[0];
        ((uint4*)dstA)[1] = ((const uint4*)src)[1];
      } else {
        const float* src = (const float*)Aptr + (size_t)(bm * 128 + srow) * K + kt * 32 + sseg * 16;
        float4 f0 = ((const float4*)src)[0];
        float4 f1 = ((const float4*)src)[1];
        float4 f2 = ((const float4*)src)[2];
        float4 f3 = ((const float4*)src)[3];
        uint4 o0, o1;
        o0.x = f2bf(f0.x) | ((unsigned)f2bf(f0.y) << 16);
        o0.y = f2bf(f0.z) | ((unsigned)f2bf(f0.w) << 16);
        o0.z = f2bf(f1.x) | ((unsigned)f2bf(f1.y) << 16);
        o0.w = f2bf(f1.z) | ((unsigned)f2bf(f1.w) << 16);
        o1.x = f2bf(f2.x) | ((unsigned)f2bf(f2.y) << 16);
        o1.y = f2bf(f2.z) | ((unsigned)f2bf(f2.w) << 16);
        o1.z = f2bf(f3.x) | ((unsigned)f2bf(f3.y) << 16);
        o1.w = f2bf(f3.z) | ((unsigned)f2bf(f3.w) << 16);
        ((uint4*)dstA)[0] = o0;
        ((uint4*)dstA)[1] = o1;
      }
      // ---- stage B tile (128 x 32) as bf16 ----
      const float* srcB = Bptr + (size_t)(bn * 128 + srow) * K + kt * 32 + sseg * 16;
      float4 g0 = ((const float4*)srcB)[0];
      float4 g1 = ((const float4*)srcB)[1];
      float4 g2 = ((const float4*)srcB)[2];
      float4 g3 = ((const float4*)srcB)[3];
      uint4 b0, b1;
      b0.x = f2bf(g0.x) | ((unsigned)f2bf(g0.y) << 16);
      b0.y = f2bf(g0.z) | ((unsigned)f2bf(g0.w) << 16);
      b0.z = f2bf(g1.x) | ((unsigned)f2bf(g1.y) << 16);
      b0.w = f2bf(g1.z) | ((unsigned)f2bf(g1.w) << 16);
      b1.x = f2bf(g2.x) | ((unsigned)f2bf(g2.y) << 16);
      b1.y = f2bf(g2.z) | ((unsigned)f2bf(g2.w) << 16);
      b1.z = f2bf(g3.x) | ((unsigned)f2bf(g3.y) << 16);
      b1.w = f2bf(g3.z) | ((unsigned)f2bf(g3.w) << 16);
      unsigned short* dstB = &Blds[srow][sseg * 16];
      ((uint4*)dstB)[0] = b0;
      ((uint4*)dstB)[1] = b1;
    }
    __syncthreads();

    bf16x8 af[4], bfv[4];
#pragma unroll
    for (int mi = 0; mi < 4; ++mi)
      af[mi] = *(const bf16x8*)&Alds[wr * 64 + mi * 16 + lr][lg * 8];
#pragma unroll
    for (int ni = 0; ni < 4; ++ni)
      bfv[ni] = *(const bf16x8*)&Blds[wc * 64 + ni * 16 + lr][lg * 8];
#pragma unroll
    for (int mi = 0; mi < 4; ++mi)
#pragma unroll
      for (int ni = 0; ni < 4; ++ni)
        acc[mi][ni] = MFMA16(af[mi], bfv[ni], acc[mi][ni]);
  }

#pragma unroll
  for (int mi = 0; mi < 4; ++mi) {
#pragma unroll
    for (int r = 0; r < 4; ++r) {
      const int m = bm * 128 + wr * 64 + mi * 16 + lg * 4 + r;
#pragma unroll
      for (int ni = 0; ni < 4; ++ni) {
        const int n = bn * 128 + wc * 64 + ni * 16 + lr;
        float v = acc[mi][ni][r];
        if constexpr (C_BF16)
          ((unsigned short*)Cptr)[(size_t)m * N + n] = f2bf(v);
        else
          ((float*)Cptr)[(size_t)m * N + n] = v;
      }
    }
  }
}

// Flash-style causal attention.
// Q/K/V/O: bf16 bits, layout [b][t][h*64+d], row stride 1024.
// Block: (q-tile of 64, head, batch); 4 waves, wave w handles q rows [q0+16w, q0+16w+16).
__global__ __launch_bounds__(256) void flash_attn(const unsigned short* __restrict__ Qb,
                                                  const unsigned short* __restrict__ Kb,
                                                  const unsigned short* __restrict__ Vb,
                                                  unsigned short* __restrict__ Ob) {
  __shared__ unsigned short Klds[32][72];   // [kv][d] row-major
  __shared__ unsigned short Vlds[64][40];   // transposed: [d][kv]
  __shared__ unsigned short Plds[4][16][40];
  const int tid = threadIdx.x, wid = tid >> 6, lane = tid & 63;
  const int lg = lane >> 4, lr = lane & 15;
  const int q0 = blockIdx.x * 64;
  const int hh = blockIdx.y, bb = blockIdx.z;
  const size_t base = ((size_t)bb * 2048) * 1024 + (size_t)hh * 64;

  bf16x8 qf0, qf1;
  {
    const unsigned short* qp = Qb + base + (size_t)(q0 + wid * 16 + lr) * 1024 + lg * 8;
    qf0 = *(const bf16x8*)qp;         // d in [0,32)
    qf1 = *(const bf16x8*)(qp + 32);  // d in [32,64)
  }
  f32x4 acc[4];
#pragma unroll
  for (int dt = 0; dt < 4; ++dt) acc[dt] = {0.f, 0.f, 0.f, 0.f};
  float m_r[4], l_r[4];
#pragma unroll
  for (int r = 0; r < 4; ++r) {
    m_r[r] = -1e30f;
    l_r[r] = 0.f;
  }

  const int ntiles = (q0 >> 5) + 2;
  const int srow = tid >> 3, sc8 = (tid & 7) * 8;
  const int qgbase = q0 + wid * 16 + lg * 4;

  for (int t = 0; t < ntiles; ++t) {
    const int kv0 = t * 32;
    __syncthreads();
    {
      const uint4 kvec = *(const uint4*)(Kb + base + (size_t)(kv0 + srow) * 1024 + sc8);
      *(uint4*)&Klds[srow][sc8] = kvec;
      const uint4 vvec = *(const uint4*)(Vb + base + (size_t)(kv0 + srow) * 1024 + sc8);
      const unsigned short* vs = (const unsigned short*)&vvec;
#pragma unroll
      for (int j = 0; j < 8; ++j) Vlds[sc8 + j][srow] = vs[j];
    }
    __syncthreads();

    // S = Q K^T for this wave's 16 q rows x 32 kv
    f32x4 s0 = {0.f, 0.f, 0.f, 0.f}, s1 = {0.f, 0.f, 0.f, 0.f};
    {
      bf16x8 b00 = *(const bf16x8*)&Klds[lr][lg * 8];
      bf16x8 b01 = *(const bf16x8*)&Klds[lr][32 + lg * 8];
      bf16x8 b10 = *(const bf16x8*)&Klds[16 + lr][lg * 8];
      bf16x8 b11 = *(const bf16x8*)&Klds[16 + lr][32 + lg * 8];
      s0 = MFMA16(qf0, b00, s0);
      s0 = MFMA16(qf1, b01, s0);
      s1 = MFMA16(qf0, b10, s1);
      s1 = MFMA16(qf1, b11, s1);
    }

    float p0[4], p1[4], tmax[4];
#pragma unroll
    for (int r = 0; r < 4; ++r) {
      float v0 = s0[r] * 0.03125f;  // 1/sqrt(1024)
      float v1 = s1[r] * 0.03125f;
      if (kv0 + lr > qgbase + r) v0 = -1e30f;
      if (kv0 + 16 + lr > qgbase + r) v1 = -1e30f;
      p0[r] = v0;
      p1[r] = v1;
      tmax[r] = fmaxf(v0, v1);
    }
#pragma unroll
    for (int r = 0; r < 4; ++r) {
#pragma unroll
      for (int off = 1; off < 16; off <<= 1)
        tmax[r] = fmaxf(tmax[r], __shfl_xor(tmax[r], off));
    }
    float sf[4];
#pragma unroll
    for (int r = 0; r < 4; ++r) {
      float mn = fmaxf(m_r[r], tmax[r]);
      sf[r] = exp2f((m_r[r] - mn) * 1.44269504f);
      m_r[r] = mn;
      p0[r] = exp2f((p0[r] - mn) * 1.44269504f);
      p1[r] = exp2f((p1[r] - mn) * 1.44269504f);
    }
    float rsum[4];
#pragma unroll
    for (int r = 0; r < 4; ++r) {
      rsum[r] = p0[r] + p1[r];
#pragma unroll
      for (int off = 1; off < 16; off <<= 1) rsum[r] += __shfl_xor(rsum[r], off);
      l_r[r] = l_r[r] * sf[r] + rsum[r];
    }
#pragma unroll
    for (int dt = 0; dt < 4; ++dt)
#pragma unroll
      for (int r = 0; r < 4; ++r) acc[dt][r] *= sf[r];

    // P (C-layout) -> LDS -> A-layout
#pragma unroll
    for (int r = 0; r < 4; ++r) {
      Plds[wid][lg * 4 + r][lr] = f2bf(p0[r]);
      Plds[wid][lg * 4 + r][16 + lr] = f2bf(p1[r]);
    }
    bf16x8 pa = *(const bf16x8*)&Plds[wid][lr][lg * 8];
#pragma unroll
    for (int dt = 0; dt < 4; ++dt) {
      bf16x8 vb = *(const bf16x8*)&Vlds[dt * 16 + lr][lg * 8];
      acc[dt] = MFMA16(pa, vb, acc[dt]);
    }
  }

#pragma unroll
  for (int r = 0; r < 4; ++r) {
    float inv = 1.f / l_r[r];
    unsigned short* orow = Ob + base + (size_t)(q0 + wid * 16 + lg * 4 + r) * 1024;
#pragma unroll
    for (int dt = 0; dt < 4; ++dt) orow[dt * 16 + lr] = f2bf(acc[dt][r] * inv);
  }
}

extern "C" void kernel_launch(void* const* d_in, const int* in_sizes, int n_in, void* d_out,
                              int out_size, void* d_ws, size_t ws_size, hipStream_t stream) {
  const float* x = (const float*)d_in[0];
  const float* Wq = (const float*)d_in[1];
  const float* Wk = (const float*)d_in[2];
  const float* Wv = (const float*)d_in[3];
  const float* Wo = (const float*)d_in[4];
  float* out = (float*)d_out;

  const int M = 4096, N = 1024, K = 1024;  // M = b*t
  unsigned short* Qb = (unsigned short*)d_ws;
  unsigned short* Kb = Qb + (size_t)M * N;
  unsigned short* Vb = Kb + (size_t)M * N;
  unsigned short* Ob = Vb + (size_t)M * N;

  dim3 gg(N / 128, M / 128);
  gemm_abt<false, true><<<gg, 256, 0, stream>>>(x, Wq, Qb, M, N, K);
  gemm_abt<false, true><<<gg, 256, 0, stream>>>(x, Wk, Kb, M, N, K);
  gemm_abt<false, true><<<gg, 256, 0, stream>>>(x, Wv, Vb, M, N, K);
  flash_attn<<<dim3(2048 / 64, 16, 2), 256, 0, stream>>>(Qb, Kb, Vb, Ob);
  gemm_abt<true, false><<<gg, 256, 0, stream>>>(Ob, Wo, out, M, N, K);
}

// Round 2
// 168.157 us; speedup vs baseline: 2.3651x; 2.3651x over previous
//
#include <hip/hip_runtime.h>
#include <hip/hip_bf16.h>

typedef __attribute__((ext_vector_type(8))) short bf16x8;
typedef __attribute__((ext_vector_type(4))) float f32x4;
typedef unsigned short u16;
typedef unsigned int u32;

#define MFMA16(a, b, c) __builtin_amdgcn_mfma_f32_16x16x32_bf16((a), (b), (c), 0, 0, 0)

__device__ __forceinline__ void gld16(const void* g, void* l) {
  __builtin_amdgcn_global_load_lds((const __attribute__((address_space(1))) u32*)g,
                                   (__attribute__((address_space(3))) u32*)l, 16, 0, 0);
}

__device__ __forceinline__ u16 f2bf(float f) {
  u32 x = __float_as_uint(f);
  x += 0x7fffu + ((x >> 16) & 1u);
  return (u16)(x >> 16);
}
__device__ __forceinline__ u32 pk2(float lo, float hi) {
  return (u32)f2bf(lo) | ((u32)f2bf(hi) << 16);
}
// Read a bf16x8 fragment from a [rows][64] bf16 LDS tile with st-style XOR swizzle.
__device__ __forceinline__ bf16x8 ldfrag(const u16* lds, int row, int kbyte) {
  return *(const bf16x8*)&lds[row * 64 + ((kbyte ^ ((row & 7) << 4)) >> 1)];
}

__global__ __launch_bounds__(256) void cvt_bf16(const float* __restrict__ s, u16* __restrict__ d,
                                                int n4) {
  int i = blockIdx.x * 256 + threadIdx.x;
  if (i < n4) {
    float4 f = ((const float4*)s)[i];
    uint2 o;
    o.x = pk2(f.x, f.y);
    o.y = pk2(f.z, f.w);
    ((uint2*)d)[i] = o;
  }
}

// C = A @ W^T.  A: bf16 [4096][1024].  MODE 0: QKV fused (grid.x=24), writes Q,K bf16
// row-major and V transposed [b*1024+dg][2048].  MODE 1: out fp32 [4096][1024].
// BBF: B pre-converted bf16 (global_load_lds) vs fp32 reg-staged conversion.
template <int MODE, bool BBF>
__global__ __launch_bounds__(256) void gemm2(const u16* __restrict__ Ab,
                                             const float* __restrict__ W0,
                                             const float* __restrict__ W1,
                                             const float* __restrict__ W2,
                                             const u16* __restrict__ Bb, u16* __restrict__ Cq,
                                             u16* __restrict__ Ck, u16* __restrict__ Cvt,
                                             float* __restrict__ Cf) {
  __shared__ u16 Alds[128 * 64];
  __shared__ u16 Blds[128 * 64];
  const int tid = threadIdx.x, wid = tid >> 6, lane = tid & 63;
  const int lg = lane >> 4, lr = lane & 15;
  const int wr = wid >> 1, wc = wid & 1;
  const int bm = blockIdx.y, bn = blockIdx.x;
  const int ng = bn * 128;

  const float* Bf = nullptr;
  const u16* Bbr = nullptr;
  if constexpr (BBF) {
    Bbr = Bb + (size_t)ng * 1024;
  } else {
    if constexpr (MODE == 0)
      Bf = (ng < 1024 ? W0 : (ng < 2048 ? W1 : W2)) + (size_t)(ng & 1023) * 1024;
    else
      Bf = W0 + (size_t)ng * 1024;
  }

  f32x4 acc[4][4];
#pragma unroll
  for (int i = 0; i < 4; ++i)
#pragma unroll
    for (int j = 0; j < 4; ++j) acc[i][j] = {0.f, 0.f, 0.f, 0.f};

  const u16* Ag0 = Ab + (size_t)(bm * 128) * 1024;
  const int srow8 = lane >> 3, schunk = lane & 7;
  const int brow = tid >> 1, bhalf = tid & 1;

  for (int kt = 0; kt < 16; ++kt) {
    __syncthreads();
    // ---- A tile [128][64] via global_load_lds, swizzled source ----
#pragma unroll
    for (int c = 0; c < 4; ++c) {
      int rb = (c * 4 + wid) * 8;
      int row = rb + srow8;
      int ch = schunk ^ srow8;
      gld16(Ag0 + (size_t)row * 1024 + kt * 64 + ch * 8, (void*)&Alds[rb * 64]);
    }
    if constexpr (BBF) {
#pragma unroll
      for (int c = 0; c < 4; ++c) {
        int rb = (c * 4 + wid) * 8;
        int row = rb + srow8;
        int ch = schunk ^ srow8;
        gld16(Bbr + (size_t)row * 1024 + kt * 64 + ch * 8, (void*)&Blds[rb * 64]);
      }
    } else {
      const float* s = Bf + (size_t)brow * 1024 + kt * 64 + bhalf * 32;
#pragma unroll
      for (int q = 0; q < 4; ++q) {
        float4 f0 = ((const float4*)s)[2 * q];
        float4 f1 = ((const float4*)s)[2 * q + 1];
        uint4 w;
        w.x = pk2(f0.x, f0.y);
        w.y = pk2(f0.z, f0.w);
        w.z = pk2(f1.x, f1.y);
        w.w = pk2(f1.z, f1.w);
        int ch = (bhalf * 4 + q) ^ (brow & 7);
        *(uint4*)&Blds[brow * 64 + ch * 8] = w;
      }
    }
    __syncthreads();

#pragma unroll
    for (int ks = 0; ks < 2; ++ks) {
      bf16x8 af[4], bfr[4];
#pragma unroll
      for (int mi = 0; mi < 4; ++mi) af[mi] = ldfrag(Alds, wr * 64 + mi * 16 + lr, ks * 64 + lg * 16);
#pragma unroll
      for (int ni = 0; ni < 4; ++ni) bfr[ni] = ldfrag(Blds, wc * 64 + ni * 16 + lr, ks * 64 + lg * 16);
#pragma unroll
      for (int mi = 0; mi < 4; ++mi)
#pragma unroll
        for (int ni = 0; ni < 4; ++ni) acc[mi][ni] = MFMA16(af[mi], bfr[ni], acc[mi][ni]);
    }
  }

  if constexpr (MODE == 1) {
#pragma unroll
    for (int mi = 0; mi < 4; ++mi)
#pragma unroll
      for (int r = 0; r < 4; ++r) {
        int m = bm * 128 + wr * 64 + mi * 16 + lg * 4 + r;
#pragma unroll
        for (int ni = 0; ni < 4; ++ni)
          Cf[(size_t)m * 1024 + ng + wc * 64 + ni * 16 + lr] = acc[mi][ni][r];
      }
  } else if (ng < 2048) {
    u16* C = (ng < 1024) ? Cq : Ck;
    const int nb = ng & 1023;
#pragma unroll
    for (int mi = 0; mi < 4; ++mi)
#pragma unroll
      for (int r = 0; r < 4; ++r) {
        int m = bm * 128 + wr * 64 + mi * 16 + lg * 4 + r;
#pragma unroll
        for (int ni = 0; ni < 4; ++ni)
          C[(size_t)m * 1024 + nb + wc * 64 + ni * 16 + lr] = f2bf(acc[mi][ni][r]);
      }
  } else {
    const int bnum = (bm * 128) >> 11;
    const int nvb = (ng - 2048) + wc * 64;
#pragma unroll
    for (int mi = 0; mi < 4; ++mi) {
      int tb = ((bm * 128) & 2047) + wr * 64 + mi * 16 + lg * 4;
#pragma unroll
      for (int ni = 0; ni < 4; ++ni) {
        int nv = nvb + ni * 16 + lr;
        ushort4 st;
        st.x = f2bf(acc[mi][ni][0]);
        st.y = f2bf(acc[mi][ni][1]);
        st.z = f2bf(acc[mi][ni][2]);
        st.w = f2bf(acc[mi][ni][3]);
        *(ushort4*)&Cvt[((size_t)(bnum << 10) + nv) * 2048 + tb] = st;
      }
    }
  }
}

// Flash causal attention. Q/K row-major bf16 [b*2048][1024] (head cols h*64..),
// Vt transposed bf16 [(b*1024+h*64+d)][2048]. O written to Ob (row-major, may alias Q).
// Grid (16 pairs, 16 heads, 2 batch); block 256 = 4 waves x 16 q-rows; kv tiles of 64.
__global__ __launch_bounds__(256) void flash2(const u16* __restrict__ Qb,
                                              const u16* __restrict__ Kb,
                                              const u16* __restrict__ Vt, u16* __restrict__ Ob) {
  __shared__ u16 Klds[64 * 64];
  __shared__ u16 Vlds[64 * 64];
  __shared__ u16 Plds[4][16][72];
  const int tid = threadIdx.x, wid = tid >> 6, lane = tid & 63;
  const int lg = lane >> 4, lr = lane & 15;
  const int hh = blockIdx.y, bb = blockIdx.z;
  const size_t baseqk = ((size_t)bb * 2048) * 1024 + hh * 64;
  const u16* Vth = Vt + ((size_t)(bb * 1024 + hh * 64)) * 2048;
  const int srow8 = lane >> 3, schunk = lane & 7;

  for (int half = 0; half < 2; ++half) {
    const int jq = half ? (31 - blockIdx.x) : blockIdx.x;
    const int q0 = jq * 64;
    bf16x8 qf0, qf1;
    {
      const u16* qp = Qb + baseqk + (size_t)(q0 + wid * 16 + lr) * 1024 + lg * 8;
      qf0 = *(const bf16x8*)qp;
      qf1 = *(const bf16x8*)(qp + 32);
    }
    f32x4 acc[4];
#pragma unroll
    for (int dt = 0; dt < 4; ++dt) acc[dt] = {0.f, 0.f, 0.f, 0.f};
    float m_r[4], l_r[4];
#pragma unroll
    for (int r = 0; r < 4; ++r) {
      m_r[r] = -1e30f;
      l_r[r] = 0.f;
    }
    const int qrow0 = q0 + wid * 16 + lg * 4;

    for (int t = 0; t <= jq; ++t) {
      const int kv0 = t * 64;
      __syncthreads();
#pragma unroll
      for (int c = 0; c < 2; ++c) {
        int rb = (c * 4 + wid) * 8;
        int row = rb + srow8;
        int ch = schunk ^ srow8;
        gld16(Kb + baseqk + (size_t)(kv0 + row) * 1024 + ch * 8, (void*)&Klds[rb * 64]);
        gld16(Vth + (size_t)row * 2048 + kv0 + ch * 8, (void*)&Vlds[rb * 64]);
      }
      __syncthreads();

      f32x4 s[4];
#pragma unroll
      for (int ni = 0; ni < 4; ++ni) s[ni] = {0.f, 0.f, 0.f, 0.f};
#pragma unroll
      for (int ks = 0; ks < 2; ++ks) {
        bf16x8 qa = ks ? qf1 : qf0;
#pragma unroll
        for (int ni = 0; ni < 4; ++ni) {
          bf16x8 kb = ldfrag(Klds, ni * 16 + lr, ks * 64 + lg * 16);
          s[ni] = MFMA16(qa, kb, s[ni]);
        }
      }

      float p[4][4], tmax[4];
      const bool diag = (t == jq);
#pragma unroll
      for (int r = 0; r < 4; ++r) tmax[r] = -1e30f;
#pragma unroll
      for (int ni = 0; ni < 4; ++ni)
#pragma unroll
        for (int r = 0; r < 4; ++r) {
          float v = s[ni][r] * 0.03125f;  // 1/sqrt(1024)
          if (diag && (kv0 + ni * 16 + lr > qrow0 + r)) v = -1e30f;
          p[ni][r] = v;
          tmax[r] = fmaxf(tmax[r], v);
        }
#pragma unroll
      for (int r = 0; r < 4; ++r) {
#pragma unroll
        for (int off = 1; off < 16; off <<= 1) tmax[r] = fmaxf(tmax[r], __shfl_xor(tmax[r], off));
      }
      float sf[4];
#pragma unroll
      for (int r = 0; r < 4; ++r) {
        float mn = fmaxf(m_r[r], tmax[r]);
        sf[r] = exp2f((m_r[r] - mn) * 1.44269504f);
        m_r[r] = mn;
        float rs = 0.f;
#pragma unroll
        for (int ni = 0; ni < 4; ++ni) {
          p[ni][r] = exp2f((p[ni][r] - mn) * 1.44269504f);
          rs += p[ni][r];
        }
#pragma unroll
        for (int off = 1; off < 16; off <<= 1) rs += __shfl_xor(rs, off);
        l_r[r] = l_r[r] * sf[r] + rs;
      }
#pragma unroll
      for (int dt = 0; dt < 4; ++dt)
#pragma unroll
        for (int r = 0; r < 4; ++r) acc[dt][r] *= sf[r];

      // P (C-layout) -> LDS -> A-layout
#pragma unroll
      for (int ni = 0; ni < 4; ++ni)
#pragma unroll
        for (int r = 0; r < 4; ++r) Plds[wid][lg * 4 + r][ni * 16 + lr] = f2bf(p[ni][r]);
      bf16x8 pa0 = *(const bf16x8*)&Plds[wid][lr][lg * 8];
      bf16x8 pa1 = *(const bf16x8*)&Plds[wid][lr][32 + lg * 8];
#pragma unroll
      for (int dt = 0; dt < 4; ++dt) {
        bf16x8 v0 = ldfrag(Vlds, dt * 16 + lr, lg * 16);
        bf16x8 v1 = ldfrag(Vlds, dt * 16 + lr, 64 + lg * 16);
        acc[dt] = MFMA16(pa0, v0, acc[dt]);
        acc[dt] = MFMA16(pa1, v1, acc[dt]);
      }
    }

#pragma unroll
    for (int r = 0; r < 4; ++r) {
      float inv = 1.f / l_r[r];
      u16* orow = Ob + baseqk + (size_t)(q0 + wid * 16 + lg * 4 + r) * 1024;
#pragma unroll
      for (int dt = 0; dt < 4; ++dt) orow[dt * 16 + lr] = f2bf(acc[dt][r] * inv);
    }
  }
}

extern "C" void kernel_launch(void* const* d_in, const int* in_sizes, int n_in, void* d_out,
                              int out_size, void* d_ws, size_t ws_size, hipStream_t stream) {
  const float* x = (const float*)d_in[0];
  const float* Wq = (const float*)d_in[1];
  const float* Wk = (const float*)d_in[2];
  const float* Wv = (const float*)d_in[3];
  const float* Wo = (const float*)d_in[4];
  float* out = (float*)d_out;

  u16* xb = (u16*)d_ws;                     // [4096][1024] bf16  (8 MB)
  u16* Qb = xb + (size_t)4096 * 1024;       // 8 MB
  u16* Kb = Qb + (size_t)4096 * 1024;       // 8 MB
  u16* Vt = Kb + (size_t)4096 * 1024;       // 8 MB (transposed V)
  u16* Ob = Qb;                             // O overwrites Q (safe: per-block RAW order)
  u16* Wb = Vt + (size_t)4096 * 1024;       // [3072][1024] bf16 (6 MB)  -- full path only
  u16* Wob = Wb + (size_t)3072 * 1024;      // [1024][1024] bf16 (2 MB)

  const bool full = ws_size >= ((size_t)40 << 20);

  cvt_bf16<<<4096, 256, 0, stream>>>(x, xb, 4096 * 1024 / 4);
  if (full) {
    cvt_bf16<<<1024, 256, 0, stream>>>(Wq, Wb, 1024 * 1024 / 4);
    cvt_bf16<<<1024, 256, 0, stream>>>(Wk, Wb + (size_t)1024 * 1024, 1024 * 1024 / 4);
    cvt_bf16<<<1024, 256, 0, stream>>>(Wv, Wb + (size_t)2048 * 1024, 1024 * 1024 / 4);
    cvt_bf16<<<1024, 256, 0, stream>>>(Wo, Wob, 1024 * 1024 / 4);
    gemm2<0, true><<<dim3(24, 32), 256, 0, stream>>>(xb, nullptr, nullptr, nullptr, Wb, Qb, Kb,
                                                     Vt, nullptr);
    flash2<<<dim3(16, 16, 2), 256, 0, stream>>>(Qb, Kb, Vt, Ob);
    gemm2<1, true><<<dim3(8, 32), 256, 0, stream>>>(Ob, nullptr, nullptr, nullptr, Wob, nullptr,
                                                    nullptr, nullptr, out);
  } else {
    gemm2<0, false><<<dim3(24, 32), 256, 0, stream>>>(xb, Wq, Wk, Wv, nullptr, Qb, Kb, Vt,
                                                      nullptr);
    flash2<<<dim3(16, 16, 2), 256, 0, stream>>>(Qb, Kb, Vt, Ob);
    gemm2<1, false><<<dim3(8, 32), 256, 0, stream>>>(Ob, Wo, nullptr, nullptr, nullptr, nullptr,
                                                     nullptr, nullptr, out);
  }
}